// Round 6
// baseline (343.577 us; speedup 1.0000x reference)
//
#include <hip/hip_runtime.h>
#include <hip/hip_cooperative_groups.h>
#include <math.h>

namespace cg = cooperative_groups;

// Problem constants (SelectiveSSM)
#define BATCH   2
#define SEQLEN  512
#define DI      4096      // d_inner
#define DS      16        // d_state
#define RDT     128       // dt_rank
#define RTOT    160       // dt_rank + 2*d_state
#define BL      1024      // BATCH*SEQLEN rows

#define KSPLIT  32        // GEMM1 k-split: 4096/32 = 128 per block
#define KSL     (DI / KSPLIT)

#define TC  64
#define TCP 68
#define NCH (SEQLEN / TC)

typedef __bf16 bf16;
typedef bf16  bf16x8 __attribute__((ext_vector_type(8)));
typedef bf16  bf16x4 __attribute__((ext_vector_type(4)));
typedef float f32x4  __attribute__((ext_vector_type(4)));

// 16-lane (DPP row) sum reduction on the VALU pipe; result in lane 15 of row.
__device__ __forceinline__ float row16_reduce_add(float p) {
  p += __int_as_float(__builtin_amdgcn_update_dpp(
      0, __float_as_int(p), 0x111, 0xf, 0xf, true));  // row_shr:1
  p += __int_as_float(__builtin_amdgcn_update_dpp(
      0, __float_as_int(p), 0x112, 0xf, 0xf, true));  // row_shr:2
  p += __int_as_float(__builtin_amdgcn_update_dpp(
      0, __float_as_int(p), 0x114, 0xf, 0xf, true));  // row_shr:4
  p += __int_as_float(__builtin_amdgcn_update_dpp(
      0, __float_as_int(p), 0x118, 0xf, 0xf, true));  // row_shr:8
  return p;
}

__device__ __forceinline__ bf16x8 cvt_bf16x8(float4 a0, float4 a1) {
  bf16x8 r;
  r[0] = (bf16)a0.x; r[1] = (bf16)a0.y; r[2] = (bf16)a0.z; r[3] = (bf16)a0.w;
  r[4] = (bf16)a1.x; r[5] = (bf16)a1.y; r[6] = (bf16)a1.z; r[7] = (bf16)a1.w;
  return r;
}

struct __align__(16) ScanLds {
  float dtS[16][TCP];  // [dc][t]
  float xS[16][TCP];   // [dc][t]
  float BS[16][TCP];   // [n][t]
  float CS[16][TCP];   // [n][t]
  float yS[TC][16];    // [t][dc]
};

// ---------------------------------------------------------------------------
// Phase B: one 64-row x 160-col x 128-K GEMM1 tile. vb = 0..511 (mb*32+ks),
// t = 0..255 within the tile team. W converted fp32->bf16 in-register.
// ---------------------------------------------------------------------------
__device__ __forceinline__ void phaseB_gemm(const float* __restrict__ x,
                                            const float* __restrict__ W,
                                            float* __restrict__ part,
                                            int vb, int t) {
  const int w4 = t >> 6;
  const int lane = t & 63;
  const int m = lane & 15;
  const int q = lane >> 4;
  const int mb = vb >> 5;         // 0..15 M-tile
  const int ks = vb & 31;         // 0..31 k-split
  const int row0 = mb * 64 + 16 * w4;
  const int k0 = ks * KSL;        // 128-wide K slice

  f32x4 acc[10] = {};
  const float* ap = x + (size_t)(row0 + m) * DI + k0 + 8 * q;
  const float* bp = W + (size_t)m * DI + k0 + 8 * q;

#pragma unroll
  for (int kk = 0; kk < KSL; kk += 32) {
    float4 a0 = *(const float4*)(ap + kk);
    float4 a1 = *(const float4*)(ap + kk + 4);
    bf16x8 af = cvt_bf16x8(a0, a1);
#pragma unroll
    for (int nt = 0; nt < 10; ++nt) {
      float4 b0 = *(const float4*)(bp + (size_t)nt * 16 * DI + kk);
      float4 b1 = *(const float4*)(bp + (size_t)nt * 16 * DI + kk + 4);
      bf16x8 bfv = cvt_bf16x8(b0, b1);
      acc[nt] = __builtin_amdgcn_mfma_f32_16x16x32_bf16(af, bfv, acc[nt], 0, 0, 0);
    }
  }
  // C/D layout: col = m (N dim), row = 4q + r (M dim)
  float* pp = part + (size_t)ks * (BL * RTOT);
#pragma unroll
  for (int nt = 0; nt < 10; ++nt)
#pragma unroll
    for (int r = 0; r < 4; ++r)
      pp[(size_t)(row0 + 4 * q + r) * RTOT + nt * 16 + m] = acc[nt][r];
}

// ---------------------------------------------------------------------------
// Phase C: reduce 32 k-splits. gtid in [0, 40960): 4 consecutive outputs.
// ---------------------------------------------------------------------------
__device__ __forceinline__ void phaseC_reduce(const float* __restrict__ part,
                                              float* __restrict__ BCf,
                                              bf16* __restrict__ dtinb,
                                              int gtid) {
  if (gtid >= BL * RTOT / 4) return;
  const int o = gtid * 4;
  float4 s = make_float4(0.f, 0.f, 0.f, 0.f);
#pragma unroll
  for (int k = 0; k < KSPLIT; ++k) {
    float4 v = *(const float4*)&part[(size_t)k * (BL * RTOT) + o];
    s.x += v.x; s.y += v.y; s.z += v.z; s.w += v.w;
  }
  const int row = o / RTOT;
  const int col = o - row * RTOT;  // multiple of 4; never straddles rows
  if (col < RDT) {
    bf16x4 ob;
    ob[0] = (bf16)s.x; ob[1] = (bf16)s.y; ob[2] = (bf16)s.z; ob[3] = (bf16)s.w;
    *(bf16x4*)(dtinb + (size_t)row * RDT + col) = ob;
  } else {
    *(float4*)&BCf[(size_t)row * 32 + (col - RDT)] = s;
  }
}

// ---------------------------------------------------------------------------
// Phase D: fused dt-MFMA + softplus + selective scan for one scan group
// (one batch x 16 channels). group = 0..511, t = 0..255 within the group.
// NOTE: __syncthreads() inside syncs the whole (possibly 512-thread) block;
// co-located groups run the same loop shape, so barriers stay aligned.
// ---------------------------------------------------------------------------
__device__ __forceinline__ void phaseD_scan(ScanLds& L,
                                            const float* __restrict__ x,
                                            const float* __restrict__ A_log,
                                            const float* __restrict__ Dvec,
                                            const float* __restrict__ BCf,
                                            const bf16* __restrict__ dtin,
                                            const float* __restrict__ dtw,
                                            const float* __restrict__ dtb,
                                            float* __restrict__ out,
                                            int group, int t) {
  const int b = group >> 8;
  const int d0 = (group & 255) * 16;
  const int n = t & 15;             // state (scan) / MFMA m
  const int dc = t >> 4;            // channel (scan), 0..15
  const int d = d0 + dc;
  const int w = t >> 6;             // wave-in-group (dt-MFMA staging), 0..3
  const int m = t & 15;
  const int q = (t >> 4) & 3;

  const float A = -expf(A_log[d * DS + n]);
  const float Dd = Dvec[d];
  const float bias = dtb[d0 + m];

  // dtw B-fragments: chunk-invariant, fp32 -> bf16 in-reg
  bf16x8 bfragW[4];
#pragma unroll
  for (int k = 0; k < 4; ++k) {
    const float* wp = dtw + (size_t)(d0 + m) * RDT + 32 * k + 8 * q;
    bfragW[k] = cvt_bf16x8(*(const float4*)wp, *(const float4*)(wp + 4));
  }

  // loader mapping: thread -> row lt (0..63), 4-elem slice lf
  const int lt = t >> 2;
  const int lf = (t & 3) * 4;
  const int rowbase = b * SEQLEN;

  // prefetch chunk 0
  bf16x8 afrag[4];
  float4 rx, rB, rC;
  {
    const int arow = rowbase + 16 * w + m;
#pragma unroll
    for (int k = 0; k < 4; ++k)
      afrag[k] = *(const bf16x8*)(dtin + (size_t)arow * RDT + 32 * k + 8 * q);
    const int row = rowbase + lt;
    rx = *(const float4*)&x[(size_t)row * DI + d0 + lf];
    rB = *(const float4*)&BCf[row * 32 + lf];
    rC = *(const float4*)&BCf[row * 32 + 16 + lf];
  }

  float h = 0.f;

  for (int c = 0; c < NCH; ++c) {
    if (c > 0) __syncthreads();   // prev compute (LDS reads + yS writes) done

    // ---- stage dt via MFMA + softplus ----
    {
      f32x4 acc = {};
#pragma unroll
      for (int k = 0; k < 4; ++k)
        acc = __builtin_amdgcn_mfma_f32_16x16x32_bf16(afrag[k], bfragW[k], acc, 0, 0, 0);
      // D layout: col m = channel, row 4q+r = timestep within 16-row tile
#pragma unroll
      for (int r = 0; r < 4; ++r) {
        const float z = acc[r] + bias;
        L.dtS[m][16 * w + 4 * q + r] = (z > 20.f) ? z : __logf(1.f + __expf(z));
      }
    }
    // ---- stage x, B, C (transposed) ----
    {
      const float rxa[4] = {rx.x, rx.y, rx.z, rx.w};
      const float rBa[4] = {rB.x, rB.y, rB.z, rB.w};
      const float rCa[4] = {rC.x, rC.y, rC.z, rC.w};
#pragma unroll
      for (int j = 0; j < 4; ++j) {
        L.xS[lf + j][lt] = rxa[j];
        L.BS[lf + j][lt] = rBa[j];
        L.CS[lf + j][lt] = rCa[j];
      }
    }
    // ---- store previous chunk's y ----
    if (c > 0) {
      const int prow = rowbase + (c - 1) * TC + lt;
      float4 yv = *(const float4*)&L.yS[lt][lf];
      *(float4*)&out[(size_t)prow * DI + d0 + lf] = yv;
    }

    __syncthreads();              // tiles ready; yS reads done

    // ---- prefetch next chunk ----
    if (c < NCH - 1) {
      const int arow = rowbase + (c + 1) * TC + 16 * w + m;
#pragma unroll
      for (int k = 0; k < 4; ++k)
        afrag[k] = *(const bf16x8*)(dtin + (size_t)arow * RDT + 32 * k + 8 * q);
      const int row = rowbase + (c + 1) * TC + lt;
      rx = *(const float4*)&x[(size_t)row * DI + d0 + lf];
      rB = *(const float4*)&BCf[row * 32 + lf];
      rC = *(const float4*)&BCf[row * 32 + 16 + lf];
    }

    // ---- 64 steps: 8 groups of 8, explicit register batches ----
    for (int g = 0; g < 8; ++g) {
      const int t0 = 8 * g;
      const float4 dv0 = *(const float4*)&L.dtS[dc][t0];
      const float4 dv1 = *(const float4*)&L.dtS[dc][t0 + 4];
      const float4 xv0 = *(const float4*)&L.xS[dc][t0];
      const float4 xv1 = *(const float4*)&L.xS[dc][t0 + 4];
      const float4 Bv0 = *(const float4*)&L.BS[n][t0];
      const float4 Bv1 = *(const float4*)&L.BS[n][t0 + 4];
      const float4 Cv0 = *(const float4*)&L.CS[n][t0];
      const float4 Cv1 = *(const float4*)&L.CS[n][t0 + 4];
      const float dt[8] = {dv0.x, dv0.y, dv0.z, dv0.w, dv1.x, dv1.y, dv1.z, dv1.w};
      const float xv[8] = {xv0.x, xv0.y, xv0.z, xv0.w, xv1.x, xv1.y, xv1.z, xv1.w};
      const float Bv[8] = {Bv0.x, Bv0.y, Bv0.z, Bv0.w, Bv1.x, Bv1.y, Bv1.z, Bv1.w};
      const float Cv[8] = {Cv0.x, Cv0.y, Cv0.z, Cv0.w, Cv1.x, Cv1.y, Cv1.z, Cv1.w};

      float e[8], u[8], p[8];
#pragma unroll
      for (int j = 0; j < 8; ++j) {       // independent: pipelines freely
        e[j] = __expf(dt[j] * A);
        u[j] = dt[j] * xv[j] * Bv[j];
      }
#pragma unroll
      for (int j = 0; j < 8; ++j) {       // the only true serial chain
        h = fmaf(e[j], h, u[j]);
        p[j] = h * Cv[j];
      }
#pragma unroll
      for (int j = 0; j < 8; ++j)         // 8 independent DPP chains
        p[j] = row16_reduce_add(p[j]);
      if (n == 15) {
#pragma unroll
        for (int j = 0; j < 8; ++j)
          L.yS[t0 + j][dc] = fmaf(Dd, xv[j], p[j]);
      }
    }
  }

  __syncthreads();
  {
    const int prow = rowbase + (NCH - 1) * TC + lt;
    float4 yv = *(const float4*)&L.yS[lt][lf];
    *(float4*)&out[(size_t)prow * DI + d0 + lf] = yv;
  }
}

// ---------------------------------------------------------------------------
// Cooperative single kernel: 256 blocks x 512 threads (1 block/CU needed).
// Each block hosts TWO tile-teams / scan-groups (threads 0-255, 256-511).
// ---------------------------------------------------------------------------
__global__ __launch_bounds__(512, 2) void fused_all(
    const float* __restrict__ x,     const float* __restrict__ A_log,
    const float* __restrict__ Dvec,  const float* __restrict__ W,
    const float* __restrict__ dtw,   const float* __restrict__ dtb,
    float* __restrict__ part,        float* __restrict__ BCf,
    bf16* __restrict__ dtinb,        float* __restrict__ out) {
  __shared__ ScanLds L[2];
  const int tid = threadIdx.x;
  const int bid = blockIdx.x;       // 0..255
  const int half = tid >> 8;        // 0 or 1
  const int t = tid & 255;

  cg::grid_group grid = cg::this_grid();

  phaseB_gemm(x, W, part, bid * 2 + half, t);

  __threadfence();
  grid.sync();

  phaseC_reduce(part, BCf, dtinb, bid * 512 + tid);

  __threadfence();
  grid.sync();

  phaseD_scan(L[half], x, A_log, Dvec, BCf, dtinb, dtw, dtb, out,
              bid * 2 + half, t);
}

// ---------------------------------------------------------------------------
// Fallback pipeline (no grid sync): 3 kernels using the same phase code.
// ---------------------------------------------------------------------------
__global__ __launch_bounds__(512, 2) void fb_gemm(const float* __restrict__ x,
                                                  const float* __restrict__ W,
                                                  float* __restrict__ part) {
  phaseB_gemm(x, W, part, blockIdx.x * 2 + (threadIdx.x >> 8), threadIdx.x & 255);
}

__global__ __launch_bounds__(512) void fb_reduce(const float* __restrict__ part,
                                                 float* __restrict__ BCf,
                                                 bf16* __restrict__ dtinb) {
  phaseC_reduce(part, BCf, dtinb, blockIdx.x * 512 + threadIdx.x);
}

__global__ __launch_bounds__(512, 2) void fb_scan(
    const float* __restrict__ x, const float* __restrict__ A_log,
    const float* __restrict__ Dvec, const float* __restrict__ BCf,
    const bf16* __restrict__ dtin, const float* __restrict__ dtw,
    const float* __restrict__ dtb, float* __restrict__ out) {
  __shared__ ScanLds L[2];
  const int half = threadIdx.x >> 8;
  phaseD_scan(L[half], x, A_log, Dvec, BCf, dtin, dtw, dtb, out,
              blockIdx.x * 2 + half, threadIdx.x & 255);
}

// ---------------------------------------------------------------------------
extern "C" void kernel_launch(void* const* d_in, const int* in_sizes, int n_in,
                              void* d_out, int out_size, void* d_ws, size_t ws_size,
                              hipStream_t stream) {
  const float* x     = (const float*)d_in[0];  // (2,512,4096)
  const float* A_log = (const float*)d_in[1];  // (4096,16)
  const float* Dv    = (const float*)d_in[2];  // (4096,)
  const float* W     = (const float*)d_in[3];  // (160,4096)
  const float* dtw   = (const float*)d_in[4];  // (4096,128)
  const float* dtb   = (const float*)d_in[5];  // (4096,)
  float* out = (float*)d_out;

  // Workspace (~21.4 MB)
  char* ws = (char*)d_ws;
  float* part  = (float*)ws;                   // 32*1024*160*4 = 20,971,520 B
  float* BCf   = (float*)(ws + 20971520);      //    131,072 B
  bf16*  dtinb = (bf16*)(ws + 21102592);       //    262,144 B

  void* args[] = {(void*)&x, (void*)&A_log, (void*)&Dv, (void*)&W, (void*)&dtw,
                  (void*)&dtb, (void*)&part, (void*)&BCf, (void*)&dtinb, (void*)&out};
  hipError_t err = hipLaunchCooperativeKernel((void*)fused_all, dim3(256),
                                              dim3(512), args, 0, stream);
  if (err != hipSuccess) {
    (void)hipGetLastError();   // clear sticky error; take the safe path
    fb_gemm<<<dim3(256), 512, 0, stream>>>(x, W, part);
    fb_reduce<<<dim3(80), 512, 0, stream>>>(part, BCf, dtinb);
    fb_scan<<<dim3(256), 512, 0, stream>>>(x, A_log, Dv, BCf, dtinb, dtw, dtb, out);
  }
}

// Round 7
// 194.249 us; speedup vs baseline: 1.7687x; 1.7687x over previous
//
#include <hip/hip_runtime.h>
#include <math.h>

// Problem constants (SelectiveSSM)
#define BATCH   2
#define SEQLEN  512
#define DI      4096      // d_inner
#define DS      16        // d_state
#define RDT     128       // dt_rank
#define RTOT    160       // dt_rank + 2*d_state
#define BL      1024      // BATCH*SEQLEN rows

#define TC  64
#define TCP 68
#define NCH (SEQLEN / TC)

typedef __bf16 bf16;
typedef bf16  bf16x8 __attribute__((ext_vector_type(8)));
typedef bf16  bf16x4 __attribute__((ext_vector_type(4)));
typedef float f32x4  __attribute__((ext_vector_type(4)));

// 16-lane (DPP row) sum reduction on the VALU pipe; result in lane 15 of row.
__device__ __forceinline__ float row16_reduce_add(float p) {
  p += __int_as_float(__builtin_amdgcn_update_dpp(
      0, __float_as_int(p), 0x111, 0xf, 0xf, true));  // row_shr:1
  p += __int_as_float(__builtin_amdgcn_update_dpp(
      0, __float_as_int(p), 0x112, 0xf, 0xf, true));  // row_shr:2
  p += __int_as_float(__builtin_amdgcn_update_dpp(
      0, __float_as_int(p), 0x114, 0xf, 0xf, true));  // row_shr:4
  p += __int_as_float(__builtin_amdgcn_update_dpp(
      0, __float_as_int(p), 0x118, 0xf, 0xf, true));  // row_shr:8
  return p;
}

__device__ __forceinline__ bf16x8 cvt_bf16x8(float4 a0, float4 a1) {
  bf16x8 r;
  r[0] = (bf16)a0.x; r[1] = (bf16)a0.y; r[2] = (bf16)a0.z; r[3] = (bf16)a0.w;
  r[4] = (bf16)a1.x; r[5] = (bf16)a1.y; r[6] = (bf16)a1.z; r[7] = (bf16)a1.w;
  return r;
}

// ---------------------------------------------------------------------------
// Kernel A: GEMM1 with INTRA-BLOCK split-K. 64 blocks x 512 threads.
// Block = 16-row M-tile x 160 cols; wave w (0..7) covers K-slice [512w,512w+512).
// Tree-reduce 8 waves' accumulators through LDS (C/D layout images), then
// wave 0 writes dtin bf16 [1024][128] + BCf fp32 [1024][32] directly.
// No part buffer, no reduce kernel, no atomics.
// ---------------------------------------------------------------------------
__global__ __launch_bounds__(512) void gemm_fused(const float* __restrict__ x,
                                                  const float* __restrict__ W,
                                                  float* __restrict__ BCf,
                                                  bf16* __restrict__ dtinb) {
  __shared__ __align__(16) float img[4][16][164];   // 42 KB; 2-way conflicts max
  const int tid = threadIdx.x;
  const int w = tid >> 6;         // wave 0..7 = K-slice
  const int lane = tid & 63;
  const int m = lane & 15;
  const int q = lane >> 4;
  const int row0 = blockIdx.x * 16;
  const int k0 = w * 512;

  f32x4 acc[10] = {};
  const float* ap = x + (size_t)(row0 + m) * DI + k0 + 8 * q;
  const float* bp = W + (size_t)m * DI + k0 + 8 * q;

#pragma unroll 4
  for (int kk = 0; kk < 512; kk += 32) {
    float4 a0 = *(const float4*)(ap + kk);
    float4 a1 = *(const float4*)(ap + kk + 4);
    bf16x8 af = cvt_bf16x8(a0, a1);
#pragma unroll
    for (int nt = 0; nt < 10; ++nt) {
      float4 b0 = *(const float4*)(bp + (size_t)nt * 16 * DI + kk);
      float4 b1 = *(const float4*)(bp + (size_t)nt * 16 * DI + kk + 4);
      bf16x8 bfv = cvt_bf16x8(b0, b1);
      acc[nt] = __builtin_amdgcn_mfma_f32_16x16x32_bf16(af, bfv, acc[nt], 0, 0, 0);
    }
  }

  // ---- 8 -> 4 ----
  if (w >= 4) {
#pragma unroll
    for (int nt = 0; nt < 10; ++nt)
#pragma unroll
      for (int r = 0; r < 4; ++r)
        img[w - 4][4 * q + r][nt * 16 + m] = acc[nt][r];
  }
  __syncthreads();
  if (w < 4) {
#pragma unroll
    for (int nt = 0; nt < 10; ++nt)
#pragma unroll
      for (int r = 0; r < 4; ++r)
        acc[nt][r] += img[w][4 * q + r][nt * 16 + m];
  }
  __syncthreads();
  // ---- 4 -> 2 ----
  if (w == 2 || w == 3) {
#pragma unroll
    for (int nt = 0; nt < 10; ++nt)
#pragma unroll
      for (int r = 0; r < 4; ++r)
        img[w - 2][4 * q + r][nt * 16 + m] = acc[nt][r];
  }
  __syncthreads();
  if (w < 2) {
#pragma unroll
    for (int nt = 0; nt < 10; ++nt)
#pragma unroll
      for (int r = 0; r < 4; ++r)
        acc[nt][r] += img[w][4 * q + r][nt * 16 + m];
  }
  __syncthreads();
  // ---- 2 -> 1 ----
  if (w == 1) {
#pragma unroll
    for (int nt = 0; nt < 10; ++nt)
#pragma unroll
      for (int r = 0; r < 4; ++r)
        img[0][4 * q + r][nt * 16 + m] = acc[nt][r];
  }
  __syncthreads();
  if (w == 0) {
#pragma unroll
    for (int nt = 0; nt < 10; ++nt)
#pragma unroll
      for (int r = 0; r < 4; ++r) {
        const float v = acc[nt][r] + img[0][4 * q + r][nt * 16 + m];
        const int row = row0 + 4 * q + r;
        const int col = nt * 16 + m;
        if (col < RDT) dtinb[(size_t)row * RDT + col] = (bf16)v;
        else           BCf[(size_t)row * 32 + (col - RDT)] = v;
      }
  }
}

// ---------------------------------------------------------------------------
// Kernel B: fused dt-MFMA + softplus + selective scan (round-4 structure,
// measured 45.4 us). 512 blocks x 256 threads. dtw converted fp32->bf16
// in-register (chunk-invariant fragments).
// ---------------------------------------------------------------------------
__global__ __launch_bounds__(256) void scan_fused(const float* __restrict__ x,
                                                  const float* __restrict__ A_log,
                                                  const float* __restrict__ Dvec,
                                                  const float* __restrict__ BCf,
                                                  const bf16* __restrict__ dtin,
                                                  const float* __restrict__ dtw,
                                                  const float* __restrict__ dtb,
                                                  float* __restrict__ out) {
  __shared__ __align__(16) float dtS[16][TCP];  // [dc][t]
  __shared__ __align__(16) float xS[16][TCP];   // [dc][t]
  __shared__ __align__(16) float BS[16][TCP];   // [n][t]
  __shared__ __align__(16) float CS[16][TCP];   // [n][t]
  __shared__ __align__(16) float yS[TC][16];    // [t][dc]

  const int bid = blockIdx.x;         // 0..511
  const int b = bid >> 8;
  const int d0 = (bid & 255) * 16;
  const int tid = threadIdx.x;
  const int n = tid & 15;             // state (scan) / MFMA m
  const int dc = tid >> 4;            // channel (scan)
  const int d = d0 + dc;
  const int w = tid >> 6;             // wave id (dt-MFMA staging)
  const int m = tid & 15;
  const int q = (tid >> 4) & 3;

  const float A = -expf(A_log[d * DS + n]);
  const float Dd = Dvec[d];
  const float bias = dtb[d0 + m];

  // dtw B-fragments: chunk-invariant, fp32 -> bf16 in-reg
  bf16x8 bfragW[4];
#pragma unroll
  for (int k = 0; k < 4; ++k) {
    const float* wp = dtw + (size_t)(d0 + m) * RDT + 32 * k + 8 * q;
    bfragW[k] = cvt_bf16x8(*(const float4*)wp, *(const float4*)(wp + 4));
  }

  // loader mapping: thread -> row lt (0..63), 4-elem slice lf
  const int lt = tid >> 2;
  const int lf = (tid & 3) * 4;
  const int rowbase = b * SEQLEN;

  // prefetch chunk 0
  bf16x8 afrag[4];
  float4 rx, rB, rC;
  {
    const int arow = rowbase + 16 * w + m;
#pragma unroll
    for (int k = 0; k < 4; ++k)
      afrag[k] = *(const bf16x8*)(dtin + (size_t)arow * RDT + 32 * k + 8 * q);
    const int row = rowbase + lt;
    rx = *(const float4*)&x[(size_t)row * DI + d0 + lf];
    rB = *(const float4*)&BCf[row * 32 + lf];
    rC = *(const float4*)&BCf[row * 32 + 16 + lf];
  }

  float h = 0.f;

  for (int c = 0; c < NCH; ++c) {
    if (c > 0) __syncthreads();   // prev compute (LDS reads + yS writes) done

    // ---- stage dt via MFMA + softplus ----
    {
      f32x4 acc = {};
#pragma unroll
      for (int k = 0; k < 4; ++k)
        acc = __builtin_amdgcn_mfma_f32_16x16x32_bf16(afrag[k], bfragW[k], acc, 0, 0, 0);
      // D layout: col m = channel, row 4q+r = timestep within 16-row tile
#pragma unroll
      for (int r = 0; r < 4; ++r) {
        const float z = acc[r] + bias;
        dtS[m][16 * w + 4 * q + r] = (z > 20.f) ? z : __logf(1.f + __expf(z));
      }
    }
    // ---- stage x, B, C (transposed) ----
    {
      const float rxa[4] = {rx.x, rx.y, rx.z, rx.w};
      const float rBa[4] = {rB.x, rB.y, rB.z, rB.w};
      const float rCa[4] = {rC.x, rC.y, rC.z, rC.w};
#pragma unroll
      for (int j = 0; j < 4; ++j) {
        xS[lf + j][lt] = rxa[j];
        BS[lf + j][lt] = rBa[j];
        CS[lf + j][lt] = rCa[j];
      }
    }
    // ---- store previous chunk's y ----
    if (c > 0) {
      const int prow = rowbase + (c - 1) * TC + lt;
      float4 yv = *(const float4*)&yS[lt][lf];
      *(float4*)&out[(size_t)prow * DI + d0 + lf] = yv;
    }

    __syncthreads();              // tiles ready; yS reads done

    // ---- prefetch next chunk ----
    if (c < NCH - 1) {
      const int arow = rowbase + (c + 1) * TC + 16 * w + m;
#pragma unroll
      for (int k = 0; k < 4; ++k)
        afrag[k] = *(const bf16x8*)(dtin + (size_t)arow * RDT + 32 * k + 8 * q);
      const int row = rowbase + (c + 1) * TC + lt;
      rx = *(const float4*)&x[(size_t)row * DI + d0 + lf];
      rB = *(const float4*)&BCf[row * 32 + lf];
      rC = *(const float4*)&BCf[row * 32 + 16 + lf];
    }

    // ---- 64 steps: 8 groups of 8, explicit register batches ----
    for (int g = 0; g < 8; ++g) {
      const int t0 = 8 * g;
      const float4 dv0 = *(const float4*)&dtS[dc][t0];
      const float4 dv1 = *(const float4*)&dtS[dc][t0 + 4];
      const float4 xv0 = *(const float4*)&xS[dc][t0];
      const float4 xv1 = *(const float4*)&xS[dc][t0 + 4];
      const float4 Bv0 = *(const float4*)&BS[n][t0];
      const float4 Bv1 = *(const float4*)&BS[n][t0 + 4];
      const float4 Cv0 = *(const float4*)&CS[n][t0];
      const float4 Cv1 = *(const float4*)&CS[n][t0 + 4];
      const float dt[8] = {dv0.x, dv0.y, dv0.z, dv0.w, dv1.x, dv1.y, dv1.z, dv1.w};
      const float xv[8] = {xv0.x, xv0.y, xv0.z, xv0.w, xv1.x, xv1.y, xv1.z, xv1.w};
      const float Bv[8] = {Bv0.x, Bv0.y, Bv0.z, Bv0.w, Bv1.x, Bv1.y, Bv1.z, Bv1.w};
      const float Cv[8] = {Cv0.x, Cv0.y, Cv0.z, Cv0.w, Cv1.x, Cv1.y, Cv1.z, Cv1.w};

      float e[8], u[8], p[8];
#pragma unroll
      for (int j = 0; j < 8; ++j) {       // independent: pipelines freely
        e[j] = __expf(dt[j] * A);
        u[j] = dt[j] * xv[j] * Bv[j];
      }
#pragma unroll
      for (int j = 0; j < 8; ++j) {       // the only true serial chain
        h = fmaf(e[j], h, u[j]);
        p[j] = h * Cv[j];
      }
#pragma unroll
      for (int j = 0; j < 8; ++j)         // 8 independent DPP chains
        p[j] = row16_reduce_add(p[j]);
      if (n == 15) {
#pragma unroll
        for (int j = 0; j < 8; ++j)
          yS[t0 + j][dc] = fmaf(Dd, xv[j], p[j]);
      }
    }
  }

  __syncthreads();
  {
    const int prow = rowbase + (NCH - 1) * TC + lt;
    float4 yv = *(const float4*)&yS[lt][lf];
    *(float4*)&out[(size_t)prow * DI + d0 + lf] = yv;
  }
}

// ---------------------------------------------------------------------------
extern "C" void kernel_launch(void* const* d_in, const int* in_sizes, int n_in,
                              void* d_out, int out_size, void* d_ws, size_t ws_size,
                              hipStream_t stream) {
  const float* x     = (const float*)d_in[0];  // (2,512,4096)
  const float* A_log = (const float*)d_in[1];  // (4096,16)
  const float* Dv    = (const float*)d_in[2];  // (4096,)
  const float* W     = (const float*)d_in[3];  // (160,4096)
  const float* dtw   = (const float*)d_in[4];  // (4096,128)
  const float* dtb   = (const float*)d_in[5];  // (4096,)
  float* out = (float*)d_out;

  // Workspace: only the compact intermediates (~0.4 MB)
  char* ws = (char*)d_ws;
  float* BCf   = (float*)ws;                   // 1024*32*4  = 131,072 B
  bf16*  dtinb = (bf16*)(ws + 131072);         // 1024*128*2 = 262,144 B

  gemm_fused<<<dim3(64), 512, 0, stream>>>(x, W, BCf, dtinb);
  scan_fused<<<dim3(512), 256, 0, stream>>>(x, A_log, Dv, BCf, dtinb, dtw, dtb, out);
}

// Round 8
// 159.768 us; speedup vs baseline: 2.1505x; 1.2158x over previous
//
#include <hip/hip_runtime.h>
#include <math.h>

// Problem constants (SelectiveSSM)
#define BATCH   2
#define SEQLEN  512
#define DI      4096      // d_inner
#define DS      16        // d_state
#define RDT     128       // dt_rank
#define RTOT    160       // dt_rank + 2*d_state
#define BL      1024      // BATCH*SEQLEN rows

#define TC  64
#define TCP 68
#define NCH (SEQLEN / TC)

typedef __bf16 bf16;
typedef bf16  bf16x8 __attribute__((ext_vector_type(8)));
typedef bf16  bf16x4 __attribute__((ext_vector_type(4)));
typedef float f32x4  __attribute__((ext_vector_type(4)));

// 16-lane (DPP row) sum reduction on the VALU pipe; result in lane 15 of row.
__device__ __forceinline__ float row16_reduce_add(float p) {
  p += __int_as_float(__builtin_amdgcn_update_dpp(
      0, __float_as_int(p), 0x111, 0xf, 0xf, true));  // row_shr:1
  p += __int_as_float(__builtin_amdgcn_update_dpp(
      0, __float_as_int(p), 0x112, 0xf, 0xf, true));  // row_shr:2
  p += __int_as_float(__builtin_amdgcn_update_dpp(
      0, __float_as_int(p), 0x114, 0xf, 0xf, true));  // row_shr:4
  p += __int_as_float(__builtin_amdgcn_update_dpp(
      0, __float_as_int(p), 0x118, 0xf, 0xf, true));  // row_shr:8
  return p;
}

__device__ __forceinline__ bf16x8 cvt_bf16x8(float4 a0, float4 a1) {
  bf16x8 r;
  r[0] = (bf16)a0.x; r[1] = (bf16)a0.y; r[2] = (bf16)a0.z; r[3] = (bf16)a0.w;
  r[4] = (bf16)a1.x; r[5] = (bf16)a1.y; r[6] = (bf16)a1.z; r[7] = (bf16)a1.w;
  return r;
}

// ---------------------------------------------------------------------------
// Kernel A: GEMM1, intra-block split-K with HIGH occupancy + MLP.
// 128 blocks x 1024 threads: block = (16-row M-tile) x (80-col N-half).
// Wave w (0..15) covers K-slice [256w, 256w+256) -> full K=4096.
// Per nt: 8 independent float4 W loads batched before use (MLP ~8/wave,
// x 16 waves/CU). Tree-reduce 16->1 through LDS; wave 0 writes
// dtin bf16 [1024][128] + BCf fp32 [1024][32] directly. No part, no atomics.
// ---------------------------------------------------------------------------
__global__ __launch_bounds__(1024, 4) void gemm_fused(const float* __restrict__ x,
                                                      const float* __restrict__ W,
                                                      float* __restrict__ BCf,
                                                      bf16* __restrict__ dtinb) {
  __shared__ __align__(16) float img[8][16][84];   // 43 KB
  const int tid = threadIdx.x;
  const int w = tid >> 6;         // wave 0..15 = K-slice
  const int lane = tid & 63;
  const int m = lane & 15;
  const int q = lane >> 4;
  const int mb = blockIdx.x >> 1;  // 0..63 M-tile
  const int nh = blockIdx.x & 1;   // N-half: cols [80*nh, 80*nh+80)
  const int row0 = mb * 16;
  const int k0 = w * 256;

  f32x4 acc[5] = {};
  const float* ap = x + (size_t)(row0 + m) * DI + k0 + 8 * q;
  const float* bp = W + (size_t)(nh * 80 + m) * DI + k0 + 8 * q;

#pragma unroll
  for (int half = 0; half < 2; ++half) {
    const int kb = half * 128;
    bf16x8 af[4];
#pragma unroll
    for (int ks = 0; ks < 4; ++ks) {
      float4 a0 = *(const float4*)(ap + kb + 32 * ks);
      float4 a1 = *(const float4*)(ap + kb + 32 * ks + 4);
      af[ks] = cvt_bf16x8(a0, a1);
    }
#pragma unroll
    for (int nt = 0; nt < 5; ++nt) {
      const float* bpn = bp + (size_t)nt * 16 * DI + kb;
      float4 bb[8];
#pragma unroll
      for (int ks = 0; ks < 4; ++ks) {
        bb[2 * ks]     = *(const float4*)(bpn + 32 * ks);
        bb[2 * ks + 1] = *(const float4*)(bpn + 32 * ks + 4);
      }
#pragma unroll
      for (int ks = 0; ks < 4; ++ks) {
        bf16x8 bfv = cvt_bf16x8(bb[2 * ks], bb[2 * ks + 1]);
        acc[nt] = __builtin_amdgcn_mfma_f32_16x16x32_bf16(af[ks], bfv, acc[nt], 0, 0, 0);
      }
    }
  }

  // ---- tree reduce 16 waves -> 1 (C/D layout images in LDS) ----
  // 16 -> 8
  if (w >= 8) {
#pragma unroll
    for (int nt = 0; nt < 5; ++nt)
#pragma unroll
      for (int r = 0; r < 4; ++r)
        img[w - 8][4 * q + r][nt * 16 + m] = acc[nt][r];
  }
  __syncthreads();
  if (w < 8) {
#pragma unroll
    for (int nt = 0; nt < 5; ++nt)
#pragma unroll
      for (int r = 0; r < 4; ++r)
        acc[nt][r] += img[w][4 * q + r][nt * 16 + m];
  }
  __syncthreads();
  // 8 -> 4
  if (w >= 4 && w < 8) {
#pragma unroll
    for (int nt = 0; nt < 5; ++nt)
#pragma unroll
      for (int r = 0; r < 4; ++r)
        img[w - 4][4 * q + r][nt * 16 + m] = acc[nt][r];
  }
  __syncthreads();
  if (w < 4) {
#pragma unroll
    for (int nt = 0; nt < 5; ++nt)
#pragma unroll
      for (int r = 0; r < 4; ++r)
        acc[nt][r] += img[w][4 * q + r][nt * 16 + m];
  }
  __syncthreads();
  // 4 -> 2
  if (w == 2 || w == 3) {
#pragma unroll
    for (int nt = 0; nt < 5; ++nt)
#pragma unroll
      for (int r = 0; r < 4; ++r)
        img[w - 2][4 * q + r][nt * 16 + m] = acc[nt][r];
  }
  __syncthreads();
  if (w < 2) {
#pragma unroll
    for (int nt = 0; nt < 5; ++nt)
#pragma unroll
      for (int r = 0; r < 4; ++r)
        acc[nt][r] += img[w][4 * q + r][nt * 16 + m];
  }
  __syncthreads();
  // 2 -> 1
  if (w == 1) {
#pragma unroll
    for (int nt = 0; nt < 5; ++nt)
#pragma unroll
      for (int r = 0; r < 4; ++r)
        img[0][4 * q + r][nt * 16 + m] = acc[nt][r];
  }
  __syncthreads();
  if (w == 0) {
#pragma unroll
    for (int nt = 0; nt < 5; ++nt)
#pragma unroll
      for (int r = 0; r < 4; ++r) {
        const float v = acc[nt][r] + img[0][4 * q + r][nt * 16 + m];
        const int row = row0 + 4 * q + r;
        const int col = nh * 80 + nt * 16 + m;
        if (col < RDT) dtinb[(size_t)row * RDT + col] = (bf16)v;
        else           BCf[(size_t)row * 32 + (col - RDT)] = v;
      }
  }
}

// ---------------------------------------------------------------------------
// Kernel B: fused dt-MFMA + softplus + selective scan (round-4 structure,
// measured 45.4 us). 512 blocks x 256 threads. dtw converted fp32->bf16
// in-register (chunk-invariant fragments).
// ---------------------------------------------------------------------------
__global__ __launch_bounds__(256) void scan_fused(const float* __restrict__ x,
                                                  const float* __restrict__ A_log,
                                                  const float* __restrict__ Dvec,
                                                  const float* __restrict__ BCf,
                                                  const bf16* __restrict__ dtin,
                                                  const float* __restrict__ dtw,
                                                  const float* __restrict__ dtb,
                                                  float* __restrict__ out) {
  __shared__ __align__(16) float dtS[16][TCP];  // [dc][t]
  __shared__ __align__(16) float xS[16][TCP];   // [dc][t]
  __shared__ __align__(16) float BS[16][TCP];   // [n][t]
  __shared__ __align__(16) float CS[16][TCP];   // [n][t]
  __shared__ __align__(16) float yS[TC][16];    // [t][dc]

  const int bid = blockIdx.x;         // 0..511
  const int b = bid >> 8;
  const int d0 = (bid & 255) * 16;
  const int tid = threadIdx.x;
  const int n = tid & 15;             // state (scan) / MFMA m
  const int dc = tid >> 4;            // channel (scan)
  const int d = d0 + dc;
  const int w = tid >> 6;             // wave id (dt-MFMA staging)
  const int m = tid & 15;
  const int q = (tid >> 4) & 3;

  const float A = -expf(A_log[d * DS + n]);
  const float Dd = Dvec[d];
  const float bias = dtb[d0 + m];

  // dtw B-fragments: chunk-invariant, fp32 -> bf16 in-reg
  bf16x8 bfragW[4];
#pragma unroll
  for (int k = 0; k < 4; ++k) {
    const float* wp = dtw + (size_t)(d0 + m) * RDT + 32 * k + 8 * q;
    bfragW[k] = cvt_bf16x8(*(const float4*)wp, *(const float4*)(wp + 4));
  }

  // loader mapping: thread -> row lt (0..63), 4-elem slice lf
  const int lt = tid >> 2;
  const int lf = (tid & 3) * 4;
  const int rowbase = b * SEQLEN;

  // prefetch chunk 0
  bf16x8 afrag[4];
  float4 rx, rB, rC;
  {
    const int arow = rowbase + 16 * w + m;
#pragma unroll
    for (int k = 0; k < 4; ++k)
      afrag[k] = *(const bf16x8*)(dtin + (size_t)arow * RDT + 32 * k + 8 * q);
    const int row = rowbase + lt;
    rx = *(const float4*)&x[(size_t)row * DI + d0 + lf];
    rB = *(const float4*)&BCf[row * 32 + lf];
    rC = *(const float4*)&BCf[row * 32 + 16 + lf];
  }

  float h = 0.f;

  for (int c = 0; c < NCH; ++c) {
    if (c > 0) __syncthreads();   // prev compute (LDS reads + yS writes) done

    // ---- stage dt via MFMA + softplus ----
    {
      f32x4 acc = {};
#pragma unroll
      for (int k = 0; k < 4; ++k)
        acc = __builtin_amdgcn_mfma_f32_16x16x32_bf16(afrag[k], bfragW[k], acc, 0, 0, 0);
      // D layout: col m = channel, row 4q+r = timestep within 16-row tile
#pragma unroll
      for (int r = 0; r < 4; ++r) {
        const float z = acc[r] + bias;
        dtS[m][16 * w + 4 * q + r] = (z > 20.f) ? z : __logf(1.f + __expf(z));
      }
    }
    // ---- stage x, B, C (transposed) ----
    {
      const float rxa[4] = {rx.x, rx.y, rx.z, rx.w};
      const float rBa[4] = {rB.x, rB.y, rB.z, rB.w};
      const float rCa[4] = {rC.x, rC.y, rC.z, rC.w};
#pragma unroll
      for (int j = 0; j < 4; ++j) {
        xS[lf + j][lt] = rxa[j];
        BS[lf + j][lt] = rBa[j];
        CS[lf + j][lt] = rCa[j];
      }
    }
    // ---- store previous chunk's y ----
    if (c > 0) {
      const int prow = rowbase + (c - 1) * TC + lt;
      float4 yv = *(const float4*)&yS[lt][lf];
      *(float4*)&out[(size_t)prow * DI + d0 + lf] = yv;
    }

    __syncthreads();              // tiles ready; yS reads done

    // ---- prefetch next chunk ----
    if (c < NCH - 1) {
      const int arow = rowbase + (c + 1) * TC + 16 * w + m;
#pragma unroll
      for (int k = 0; k < 4; ++k)
        afrag[k] = *(const bf16x8*)(dtin + (size_t)arow * RDT + 32 * k + 8 * q);
      const int row = rowbase + (c + 1) * TC + lt;
      rx = *(const float4*)&x[(size_t)row * DI + d0 + lf];
      rB = *(const float4*)&BCf[row * 32 + lf];
      rC = *(const float4*)&BCf[row * 32 + 16 + lf];
    }

    // ---- 64 steps: 8 groups of 8, explicit register batches ----
    for (int g = 0; g < 8; ++g) {
      const int t0 = 8 * g;
      const float4 dv0 = *(const float4*)&dtS[dc][t0];
      const float4 dv1 = *(const float4*)&dtS[dc][t0 + 4];
      const float4 xv0 = *(const float4*)&xS[dc][t0];
      const float4 xv1 = *(const float4*)&xS[dc][t0 + 4];
      const float4 Bv0 = *(const float4*)&BS[n][t0];
      const float4 Bv1 = *(const float4*)&BS[n][t0 + 4];
      const float4 Cv0 = *(const float4*)&CS[n][t0];
      const float4 Cv1 = *(const float4*)&CS[n][t0 + 4];
      const float dt[8] = {dv0.x, dv0.y, dv0.z, dv0.w, dv1.x, dv1.y, dv1.z, dv1.w};
      const float xv[8] = {xv0.x, xv0.y, xv0.z, xv0.w, xv1.x, xv1.y, xv1.z, xv1.w};
      const float Bv[8] = {Bv0.x, Bv0.y, Bv0.z, Bv0.w, Bv1.x, Bv1.y, Bv1.z, Bv1.w};
      const float Cv[8] = {Cv0.x, Cv0.y, Cv0.z, Cv0.w, Cv1.x, Cv1.y, Cv1.z, Cv1.w};

      float e[8], u[8], p[8];
#pragma unroll
      for (int j = 0; j < 8; ++j) {       // independent: pipelines freely
        e[j] = __expf(dt[j] * A);
        u[j] = dt[j] * xv[j] * Bv[j];
      }
#pragma unroll
      for (int j = 0; j < 8; ++j) {       // the only true serial chain
        h = fmaf(e[j], h, u[j]);
        p[j] = h * Cv[j];
      }
#pragma unroll
      for (int j = 0; j < 8; ++j)         // 8 independent DPP chains
        p[j] = row16_reduce_add(p[j]);
      if (n == 15) {
#pragma unroll
        for (int j = 0; j < 8; ++j)
          yS[t0 + j][dc] = fmaf(Dd, xv[j], p[j]);
      }
    }
  }

  __syncthreads();
  {
    const int prow = rowbase + (NCH - 1) * TC + lt;
    float4 yv = *(const float4*)&yS[lt][lf];
    *(float4*)&out[(size_t)prow * DI + d0 + lf] = yv;
  }
}

// ---------------------------------------------------------------------------
extern "C" void kernel_launch(void* const* d_in, const int* in_sizes, int n_in,
                              void* d_out, int out_size, void* d_ws, size_t ws_size,
                              hipStream_t stream) {
  const float* x     = (const float*)d_in[0];  // (2,512,4096)
  const float* A_log = (const float*)d_in[1];  // (4096,16)
  const float* Dv    = (const float*)d_in[2];  // (4096,)
  const float* W     = (const float*)d_in[3];  // (160,4096)
  const float* dtw   = (const float*)d_in[4];  // (4096,128)
  const float* dtb   = (const float*)d_in[5];  // (4096,)
  float* out = (float*)d_out;

  // Workspace: only the compact intermediates (~0.4 MB)
  char* ws = (char*)d_ws;
  float* BCf   = (float*)ws;                   // 1024*32*4  = 131,072 B
  bf16*  dtinb = (bf16*)(ws + 131072);         // 1024*128*2 = 262,144 B

  gemm_fused<<<dim3(128), 1024, 0, stream>>>(x, W, BCf, dtinb);
  scan_fused<<<dim3(512), 256, 0, stream>>>(x, A_log, Dv, BCf, dtinb, dtw, dtb, out);
}

// Round 9
// 146.960 us; speedup vs baseline: 2.3379x; 1.0872x over previous
//
#include <hip/hip_runtime.h>
#include <math.h>

// Problem constants (SelectiveSSM)
#define BATCH   2
#define SEQLEN  512
#define DI      4096      // d_inner
#define DS      16        // d_state
#define RDT     128       // dt_rank
#define RTOT    160       // dt_rank + 2*d_state
#define BL      1024      // BATCH*SEQLEN rows

#define KSPLIT  32        // GEMM1 k-split: 4096/32 = 128 per block

#define TC  128
#define TCP 132
#define NCH (SEQLEN / TC)  // 4

typedef __bf16 bf16;
typedef bf16  bf16x8 __attribute__((ext_vector_type(8)));
typedef bf16  bf16x4 __attribute__((ext_vector_type(4)));
typedef float f32x4  __attribute__((ext_vector_type(4)));

// 16-lane (DPP row) sum reduction on the VALU pipe; result in lane 15 of row.
__device__ __forceinline__ float row16_reduce_add(float p) {
  p += __int_as_float(__builtin_amdgcn_update_dpp(
      0, __float_as_int(p), 0x111, 0xf, 0xf, true));  // row_shr:1
  p += __int_as_float(__builtin_amdgcn_update_dpp(
      0, __float_as_int(p), 0x112, 0xf, 0xf, true));  // row_shr:2
  p += __int_as_float(__builtin_amdgcn_update_dpp(
      0, __float_as_int(p), 0x114, 0xf, 0xf, true));  // row_shr:4
  p += __int_as_float(__builtin_amdgcn_update_dpp(
      0, __float_as_int(p), 0x118, 0xf, 0xf, true));  // row_shr:8
  return p;
}

__device__ __forceinline__ bf16x8 cvt_bf16x8(float4 a0, float4 a1) {
  bf16x8 r;
  r[0] = (bf16)a0.x; r[1] = (bf16)a0.y; r[2] = (bf16)a0.z; r[3] = (bf16)a0.w;
  r[4] = (bf16)a1.x; r[5] = (bf16)a1.y; r[6] = (bf16)a1.z; r[7] = (bf16)a1.w;
  return r;
}

// ---------------------------------------------------------------------------
// Kernel 1: GEMM1 split-K -> part. grid (16 M-tiles, 32 k-splits) = 512
// blocks x 256 thr -> 2 blocks/CU on ALL 256 CUs. Wave w: rows row0+16w..+15;
// K-slice 128 = 4 ksteps of 32. Per kstep: ALL 22 float4 loads issued into
// named registers, then sched_barrier(0) so the compiler cannot interleave
// cvt/MFMA into the load stream (R8 failure mode: VGPR=48, 2-at-a-time
// loads). launch_bounds(256,2) -> 256-VGPR budget.
// ---------------------------------------------------------------------------
__global__ __launch_bounds__(256, 2) void gemm_part(const float* __restrict__ x,
                                                    const float* __restrict__ W,
                                                    float* __restrict__ part) {
  const int tid = threadIdx.x;
  const int w = tid >> 6;
  const int lane = tid & 63;
  const int m = lane & 15;
  const int q = lane >> 4;
  const int row0 = blockIdx.x * 64 + 16 * w;
  const int k0 = blockIdx.y * 128;             // K slice

  f32x4 acc[10] = {};
  const float* ap = x + (size_t)(row0 + m) * DI + k0 + 8 * q;
  const float* bp = W + (size_t)m * DI + k0 + 8 * q;

#pragma unroll
  for (int ks = 0; ks < 4; ++ks) {
    const int kk = 32 * ks;
    // ---- batch ALL loads for this kstep (22 x float4 in flight) ----
    float4 a0 = *(const float4*)(ap + kk);
    float4 a1 = *(const float4*)(ap + kk + 4);
    float4 b0[10], b1[10];
#pragma unroll
    for (int nt = 0; nt < 10; ++nt) {
      const float* bpn = bp + (size_t)nt * 16 * DI + kk;
      b0[nt] = *(const float4*)(bpn);
      b1[nt] = *(const float4*)(bpn + 4);
    }
    __builtin_amdgcn_sched_barrier(0);   // loads stay batched before math
    // ---- convert + MFMA ----
    bf16x8 af = cvt_bf16x8(a0, a1);
#pragma unroll
    for (int nt = 0; nt < 10; ++nt) {
      bf16x8 bfv = cvt_bf16x8(b0[nt], b1[nt]);
      acc[nt] = __builtin_amdgcn_mfma_f32_16x16x32_bf16(af, bfv, acc[nt], 0, 0, 0);
    }
  }

  // C/D layout: col = m (N dim), row = 4q + r (M dim)
  float* pp = part + (size_t)blockIdx.y * (BL * RTOT);
#pragma unroll
  for (int nt = 0; nt < 10; ++nt)
#pragma unroll
    for (int r = 0; r < 4; ++r)
      pp[(size_t)(row0 + 4 * q + r) * RTOT + nt * 16 + m] = acc[nt][r];
}

// ---------------------------------------------------------------------------
// Kernel 2: reduce k-splits (R4-proven). grid 160 x 256; thread reduces 4
// consecutive outputs. Emits dtin bf16 [1024][128] + BCf fp32 [1024][32].
// ---------------------------------------------------------------------------
__global__ __launch_bounds__(256) void reduce_xp(const float* __restrict__ part,
                                                 float* __restrict__ BCf,
                                                 bf16* __restrict__ dtinb) {
  const int o = (blockIdx.x * 256 + threadIdx.x) * 4;
  float4 s = make_float4(0.f, 0.f, 0.f, 0.f);
#pragma unroll
  for (int k = 0; k < KSPLIT; ++k) {
    float4 v = *(const float4*)&part[(size_t)k * (BL * RTOT) + o];
    s.x += v.x; s.y += v.y; s.z += v.z; s.w += v.w;
  }
  const int row = o / RTOT;
  const int col = o - row * RTOT;   // multiple of 4; never straddles rows
  if (col < RDT) {
    bf16x4 ob;
    ob[0] = (bf16)s.x; ob[1] = (bf16)s.y; ob[2] = (bf16)s.z; ob[3] = (bf16)s.w;
    *(bf16x4*)(dtinb + (size_t)row * RDT + col) = ob;
  } else {
    *(float4*)&BCf[(size_t)row * 32 + (col - RDT)] = s;
  }
}

// ---------------------------------------------------------------------------
// Kernel 3: fused dt-MFMA + softplus + selective scan. TC=128 (4 chunks:
// halves barrier/drain overhead vs TC=64). 512 blocks x 256 threads.
// Loader mapping: lt = tid>>1 (row 0..127), half = tid&1.
//   x:  thread loads x[row lt][d0+8*half .. +8)  (2 float4)
//   BC: thread loads B row lt (half=0) or C row lt (half=1) (4 float4)
// dt-MFMA: wave w stages rows 32w..32w+31 (2 MFMA tiles).
// ---------------------------------------------------------------------------
__global__ __launch_bounds__(256, 2) void scan_fused(const float* __restrict__ x,
                                                     const float* __restrict__ A_log,
                                                     const float* __restrict__ Dvec,
                                                     const float* __restrict__ BCf,
                                                     const bf16* __restrict__ dtin,
                                                     const float* __restrict__ dtw,
                                                     const float* __restrict__ dtb,
                                                     float* __restrict__ out) {
  __shared__ __align__(16) float dtS[16][TCP];  // [dc][t]
  __shared__ __align__(16) float xS[16][TCP];   // [dc][t]
  __shared__ __align__(16) float BS[16][TCP];   // [n][t]
  __shared__ __align__(16) float CS[16][TCP];   // [n][t]
  __shared__ __align__(16) float yS[TC][16];    // [t][dc]

  const int bid = blockIdx.x;         // 0..511
  const int b = bid >> 8;
  const int d0 = (bid & 255) * 16;
  const int tid = threadIdx.x;
  const int n = tid & 15;             // state (scan) / MFMA m
  const int dc = tid >> 4;            // channel (scan)
  const int d = d0 + dc;
  const int w = tid >> 6;             // wave id (dt-MFMA staging)
  const int m = tid & 15;
  const int q = (tid >> 4) & 3;

  const float A = -expf(A_log[d * DS + n]);
  const float Dd = Dvec[d];
  const float bias = dtb[d0 + m];

  // dtw B-fragments: chunk-invariant, fp32 -> bf16 in-reg
  bf16x8 bfragW[4];
#pragma unroll
  for (int k = 0; k < 4; ++k) {
    const float* wp = dtw + (size_t)(d0 + m) * RDT + 32 * k + 8 * q;
    bfragW[k] = cvt_bf16x8(*(const float4*)wp, *(const float4*)(wp + 4));
  }

  // loader mapping
  const int lt = tid >> 1;            // 0..127
  const int half = tid & 1;           // 0/1
  const int rowbase = b * SEQLEN;

  // prefetch chunk 0
  bf16x8 afrag[2][4];
  float4 rx[2], rbc[4];
  {
#pragma unroll
    for (int tt = 0; tt < 2; ++tt) {
      const int arow = rowbase + 32 * w + 16 * tt + m;
#pragma unroll
      for (int k = 0; k < 4; ++k)
        afrag[tt][k] = *(const bf16x8*)(dtin + (size_t)arow * RDT + 32 * k + 8 * q);
    }
    const int row = rowbase + lt;
    rx[0] = *(const float4*)&x[(size_t)row * DI + d0 + 8 * half];
    rx[1] = *(const float4*)&x[(size_t)row * DI + d0 + 8 * half + 4];
#pragma unroll
    for (int j = 0; j < 4; ++j)
      rbc[j] = *(const float4*)&BCf[row * 32 + 16 * half + 4 * j];
  }

  float h = 0.f;

  for (int c = 0; c < NCH; ++c) {
    if (c > 0) __syncthreads();   // prev compute (LDS reads + yS writes) done

    // ---- stage dt via MFMA + softplus (2 tiles per wave) ----
#pragma unroll
    for (int tt = 0; tt < 2; ++tt) {
      f32x4 acc = {};
#pragma unroll
      for (int k = 0; k < 4; ++k)
        acc = __builtin_amdgcn_mfma_f32_16x16x32_bf16(afrag[tt][k], bfragW[k], acc, 0, 0, 0);
      // D layout: col m = channel, row 4q+r = timestep within 16-row tile
#pragma unroll
      for (int r = 0; r < 4; ++r) {
        const float z = acc[r] + bias;
        dtS[m][32 * w + 16 * tt + 4 * q + r] = (z > 20.f) ? z : __logf(1.f + __expf(z));
      }
    }
    // ---- stage x (transposed): xS[8*half+j][lt] ----
    {
      const float rxa[8] = {rx[0].x, rx[0].y, rx[0].z, rx[0].w,
                            rx[1].x, rx[1].y, rx[1].z, rx[1].w};
#pragma unroll
      for (int j = 0; j < 8; ++j)
        xS[8 * half + j][lt] = rxa[j];
    }
    // ---- stage B or C (transposed): (half?CS:BS)[j][lt] ----
    {
      float* basep = half ? &CS[0][0] : &BS[0][0];
      const float rb[16] = {rbc[0].x, rbc[0].y, rbc[0].z, rbc[0].w,
                            rbc[1].x, rbc[1].y, rbc[1].z, rbc[1].w,
                            rbc[2].x, rbc[2].y, rbc[2].z, rbc[2].w,
                            rbc[3].x, rbc[3].y, rbc[3].z, rbc[3].w};
#pragma unroll
      for (int j = 0; j < 16; ++j)
        basep[j * TCP + lt] = rb[j];
    }
    // ---- store previous chunk's y ----
    if (c > 0) {
      const int prow = rowbase + (c - 1) * TC + lt;
      float4 y0 = *(const float4*)&yS[lt][8 * half];
      float4 y1 = *(const float4*)&yS[lt][8 * half + 4];
      *(float4*)&out[(size_t)prow * DI + d0 + 8 * half] = y0;
      *(float4*)&out[(size_t)prow * DI + d0 + 8 * half + 4] = y1;
    }

    __syncthreads();              // tiles ready; yS reads done

    // ---- prefetch next chunk ----
    if (c < NCH - 1) {
      const int cb = (c + 1) * TC;
#pragma unroll
      for (int tt = 0; tt < 2; ++tt) {
        const int arow = rowbase + cb + 32 * w + 16 * tt + m;
#pragma unroll
        for (int k = 0; k < 4; ++k)
          afrag[tt][k] = *(const bf16x8*)(dtin + (size_t)arow * RDT + 32 * k + 8 * q);
      }
      const int row = rowbase + cb + lt;
      rx[0] = *(const float4*)&x[(size_t)row * DI + d0 + 8 * half];
      rx[1] = *(const float4*)&x[(size_t)row * DI + d0 + 8 * half + 4];
#pragma unroll
      for (int j = 0; j < 4; ++j)
        rbc[j] = *(const float4*)&BCf[row * 32 + 16 * half + 4 * j];
    }

    // ---- 128 steps: 16 groups of 8, explicit register batches ----
    for (int g = 0; g < 16; ++g) {
      const int t0 = 8 * g;
      const float4 dv0 = *(const float4*)&dtS[dc][t0];
      const float4 dv1 = *(const float4*)&dtS[dc][t0 + 4];
      const float4 xv0 = *(const float4*)&xS[dc][t0];
      const float4 xv1 = *(const float4*)&xS[dc][t0 + 4];
      const float4 Bv0 = *(const float4*)&BS[n][t0];
      const float4 Bv1 = *(const float4*)&BS[n][t0 + 4];
      const float4 Cv0 = *(const float4*)&CS[n][t0];
      const float4 Cv1 = *(const float4*)&CS[n][t0 + 4];
      const float dt[8] = {dv0.x, dv0.y, dv0.z, dv0.w, dv1.x, dv1.y, dv1.z, dv1.w};
      const float xv[8] = {xv0.x, xv0.y, xv0.z, xv0.w, xv1.x, xv1.y, xv1.z, xv1.w};
      const float Bv[8] = {Bv0.x, Bv0.y, Bv0.z, Bv0.w, Bv1.x, Bv1.y, Bv1.z, Bv1.w};
      const float Cv[8] = {Cv0.x, Cv0.y, Cv0.z, Cv0.w, Cv1.x, Cv1.y, Cv1.z, Cv1.w};

      float e[8], u[8], p[8];
#pragma unroll
      for (int j = 0; j < 8; ++j) {       // independent: pipelines freely
        e[j] = __expf(dt[j] * A);
        u[j] = dt[j] * xv[j] * Bv[j];
      }
#pragma unroll
      for (int j = 0; j < 8; ++j) {       // the only true serial chain
        h = fmaf(e[j], h, u[j]);
        p[j] = h * Cv[j];
      }
#pragma unroll
      for (int j = 0; j < 8; ++j)         // 8 independent DPP chains
        p[j] = row16_reduce_add(p[j]);
      if (n == 15) {
#pragma unroll
        for (int j = 0; j < 8; ++j)
          yS[t0 + j][dc] = fmaf(Dd, xv[j], p[j]);
      }
    }
  }

  __syncthreads();
  {
    const int prow = rowbase + (NCH - 1) * TC + lt;
    float4 y0 = *(const float4*)&yS[lt][8 * half];
    float4 y1 = *(const float4*)&yS[lt][8 * half + 4];
    *(float4*)&out[(size_t)prow * DI + d0 + 8 * half] = y0;
    *(float4*)&out[(size_t)prow * DI + d0 + 8 * half + 4] = y1;
  }
}

// ---------------------------------------------------------------------------
extern "C" void kernel_launch(void* const* d_in, const int* in_sizes, int n_in,
                              void* d_out, int out_size, void* d_ws, size_t ws_size,
                              hipStream_t stream) {
  const float* x     = (const float*)d_in[0];  // (2,512,4096)
  const float* A_log = (const float*)d_in[1];  // (4096,16)
  const float* Dv    = (const float*)d_in[2];  // (4096,)
  const float* W     = (const float*)d_in[3];  // (160,4096)
  const float* dtw   = (const float*)d_in[4];  // (4096,128)
  const float* dtb   = (const float*)d_in[5];  // (4096,)
  float* out = (float*)d_out;

  // Workspace (~21.4 MB)
  char* ws = (char*)d_ws;
  float* part  = (float*)ws;                   // 32*1024*160*4 = 20,971,520 B
  float* BCf   = (float*)(ws + 20971520);      //    131,072 B
  bf16*  dtinb = (bf16*)(ws + 21102592);       //    262,144 B

  gemm_part<<<dim3(16, KSPLIT), 256, 0, stream>>>(x, W, part);
  reduce_xp<<<dim3(160), 256, 0, stream>>>(part, BCf, dtinb);
  scan_fused<<<dim3(512), 256, 0, stream>>>(x, A_log, Dv, BCf, dtinb, dtw, dtb, out);
}